// Round 1
// baseline (945.264 us; speedup 1.0000x reference)
//
#include <hip/hip_runtime.h>
#include <stdint.h>

// Problem constants: N_S=8192, N_H=64, C=64
#define NSQ 8192

typedef __attribute__((ext_vector_type(8)))  short short8;   // 8 bf16 (4 VGPRs)
typedef __attribute__((ext_vector_type(16))) float f32x16;   // MFMA 32x32 C/D

// Workspace layout. Packed MFMA fragments first (uint4 units), then floats.
// X1hi/X1lo/X2hi/X2lo: each 65536 uint4 = 1 MB (fragment order, see k_prep).
#define WS_RS   1048576u                  // rowsum [8192] (float offset)
#define WS_W2T  (1048576u + 8192u)        // W2^T [64][64]
#define WS_FLAG (1048576u + 8192u + 4096u)
#define WS_SEGB (1048576u + 8192u + 4096u + 4u)  // segment map: 8192*256 u8 = 2 MB

// ---------------------------------------------------------------------------
// init: zero rowsum + flag, build W2T (W2T[h*64+i] = W2[i*64+h])
__global__ __launch_bounds__(256) void k_init(const float* __restrict__ W2,
                                              float* __restrict__ ws) {
    int t = threadIdx.x, b = blockIdx.x;
    ws[WS_RS + b * 256 + t] = 0.0f;   // 32 blocks x 256 = 8192
    if (b == 0) {
#pragma unroll
        for (int q = 0; q < 16; ++q) {
            int e = q * 256 + t;
            int i = e >> 6, h = e & 63;
            ws[WS_W2T + h * 64 + i] = W2[i * 64 + h];
        }
        if (t == 0) ((unsigned*)ws)[WS_FLAG] = 0u;
    }
}

// ---------------------------------------------------------------------------
// detect mask dtype from a 4 MB sample.
// f32 mask -> words == 0x3f800000 ; u8 packed -> some word > 1 ; i32 -> {0,1}
__global__ __launch_bounds__(256) void k_detect(const uint4* __restrict__ m,
                                                unsigned* __restrict__ flag) {
    __shared__ unsigned bf;
    int t = threadIdx.x;
    if (t == 0) bf = 0u;
    __syncthreads();
    size_t idx = (size_t)blockIdx.x * 256 + t;
    uint4 v = m[idx];
    unsigned a[4] = {v.x, v.y, v.z, v.w};
    unsigned lf = 0u;
#pragma unroll
    for (int q = 0; q < 4; ++q) {
        if (a[q] == 0x3f800000u) lf |= 2u;
        else if (a[q] > 1u)      lf |= 1u;
    }
    if (lf) atomicOr(&bf, lf);
    __syncthreads();
    if (t == 0 && bf) atomicOr(flag, bf);
}

// ---------------------------------------------------------------------------
// maskpack: per 32-element row-segment, set segb[row*256+seg] = 1 iff any
// mask element in the segment is nonzero. One thread per segment (2M total).
__global__ __launch_bounds__(256) void k_maskpack(const void* __restrict__ mask,
                                                  const unsigned* __restrict__ flag,
                                                  uint8_t* __restrict__ segb) {
    unsigned fl = *flag;
    size_t seg = (size_t)blockIdx.x * 256 + threadIdx.x;  // 8192*256 = 2M segs
    unsigned nz = 0u;
    if (fl & 2u) {
        const float4* m = (const float4*)mask + seg * 8;   // 32 floats
#pragma unroll
        for (int q = 0; q < 8; ++q) {
            float4 v = m[q];
            if (v.x != 0.f || v.y != 0.f || v.z != 0.f || v.w != 0.f) nz = 1u;
        }
    } else if (fl & 1u) {
        const uint4* m = (const uint4*)mask + seg * 2;     // 32 bytes
        uint4 a = m[0], b = m[1];
        if (a.x | a.y | a.z | a.w | b.x | b.y | b.z | b.w) nz = 1u;
    } else {
        const uint4* m = (const uint4*)mask + seg * 8;     // 32 i32
#pragma unroll
        for (int q = 0; q < 8; ++q) {
            uint4 v = m[q];
            if (v.x | v.y | v.z | v.w) nz = 1u;
        }
    }
    segb[seg] = (uint8_t)nz;
}

// ---------------------------------------------------------------------------
// round-to-nearest-even fp32 -> bf16 split: x ~= hi + lo
__device__ inline void bf16split(float x, unsigned short& hi, unsigned short& lo) {
    unsigned u = __float_as_uint(x);
    unsigned r = (u + 0x7fffu + ((u >> 16) & 1u)) >> 16;
    hi = (unsigned short)r;
    float res = x - __uint_as_float(r << 16);
    unsigned u2 = __float_as_uint(res);
    unsigned r2 = (u2 + 0x7fffu + ((u2 >> 16) & 1u)) >> 16;
    lo = (unsigned short)r2;
}

// ---------------------------------------------------------------------------
// fused prep: reads H' ONCE (float4), computes
//   Y[s,h]  = sum_c H'[s,c,h]*w1[c]
//   X1[s,i] = sum_h Y[s,h]*W2[i,h]
//   X2[s,c] = sum_h H'[s,c,h]*w3[h]
// then packs X1/X2 rows into split-bf16 MFMA fragment order:
//   chunk (T=s>>5, kk, h, r=s&31) = 8 bf16 of X[s][kk*16+h*8 .. +8]
//   stored at uint4 index (T*4+kk)*64 + h*32 + r
__global__ __launch_bounds__(256) void k_prep(const float* __restrict__ H,
                                              const float* __restrict__ w1,
                                              const float* __restrict__ w3,
                                              const float* __restrict__ w2t,
                                              uint4* __restrict__ X1hi,
                                              uint4* __restrict__ X1lo,
                                              uint4* __restrict__ X2hi,
                                              uint4* __restrict__ X2lo) {
    __shared__ float ylds[4][64];
    __shared__ float x1b[4][64];
    __shared__ float x2b[4][64];
    int t = threadIdx.x;
    int sl = t >> 6, l = t & 63;
    int cq = l >> 4, hq = l & 15;
    size_t s = (size_t)blockIdx.x * 4 + sl;
    const float* hp = H + s * 4096;
    float4 w3q = *(const float4*)(w3 + hq * 4);
    float4 yacc = make_float4(0.f, 0.f, 0.f, 0.f);
    float x2p[16];
#pragma unroll
    for (int cc = 0; cc < 16; ++cc) {
        int c = cq * 16 + cc;
        float4 hv = *(const float4*)(hp + c * 64 + hq * 4);
        float wc = w1[c];
        yacc.x = fmaf(hv.x, wc, yacc.x);
        yacc.y = fmaf(hv.y, wc, yacc.y);
        yacc.z = fmaf(hv.z, wc, yacc.z);
        yacc.w = fmaf(hv.w, wc, yacc.w);
        x2p[cc] = hv.x * w3q.x + hv.y * w3q.y + hv.z * w3q.z + hv.w * w3q.w;
    }
#pragma unroll
    for (int cc = 0; cc < 16; ++cc) {
        float v = x2p[cc];
        v += __shfl_xor(v, 1);
        v += __shfl_xor(v, 2);
        v += __shfl_xor(v, 4);
        v += __shfl_xor(v, 8);
        x2p[cc] = v;
    }
    if (hq == 0) {
#pragma unroll
        for (int cc = 0; cc < 16; ++cc) x2b[sl][cq * 16 + cc] = x2p[cc];
    }
    yacc.x += __shfl_xor(yacc.x, 16); yacc.x += __shfl_xor(yacc.x, 32);
    yacc.y += __shfl_xor(yacc.y, 16); yacc.y += __shfl_xor(yacc.y, 32);
    yacc.z += __shfl_xor(yacc.z, 16); yacc.z += __shfl_xor(yacc.z, 32);
    yacc.w += __shfl_xor(yacc.w, 16); yacc.w += __shfl_xor(yacc.w, 32);
    if (cq == 0) *(float4*)&ylds[sl][hq * 4] = yacc;
    __syncthreads();
    float a1 = 0.f;
#pragma unroll
    for (int h = 0; h < 64; ++h) a1 = fmaf(ylds[sl][h], w2t[h * 64 + l], a1);
    x1b[sl][l] = a1;
    __syncthreads();

    // pack phase: threads 0..63: 4 s-slots x {X1,X2} x 8 k-groups
    if (t < 64) {
        int sl2 = t >> 4;
        int q   = t & 15;
        int mat = q >> 3;       // 0 = X1, 1 = X2
        int kg  = q & 7;        // k-group of 8
        const float* src = mat ? x2b[sl2] : x1b[sl2];
        unsigned short hi8[8], lo8[8];
#pragma unroll
        for (int j = 0; j < 8; ++j) bf16split(src[kg * 8 + j], hi8[j], lo8[j]);
        int sg = blockIdx.x * 4 + sl2;
        int T = sg >> 5, r = sg & 31;
        int kk = kg >> 1, h = kg & 1;
        unsigned ci = (unsigned)((T * 4 + kk) * 64 + h * 32 + r);
        uint4 hv, lv;
        hv.x = (unsigned)hi8[0] | ((unsigned)hi8[1] << 16);
        hv.y = (unsigned)hi8[2] | ((unsigned)hi8[3] << 16);
        hv.z = (unsigned)hi8[4] | ((unsigned)hi8[5] << 16);
        hv.w = (unsigned)hi8[6] | ((unsigned)hi8[7] << 16);
        lv.x = (unsigned)lo8[0] | ((unsigned)lo8[1] << 16);
        lv.y = (unsigned)lo8[2] | ((unsigned)lo8[3] << 16);
        lv.z = (unsigned)lo8[4] | ((unsigned)lo8[5] << 16);
        lv.w = (unsigned)lo8[6] | ((unsigned)lo8[7] << 16);
        if (mat) { X2hi[ci] = hv; X2lo[ci] = lv; }
        else     { X1hi[ci] = hv; X1lo[ci] = lv; }
    }
}

// ---------------------------------------------------------------------------
// main: 128x128 tile per block, 4 independent waves (NO LDS, NO barriers).
// GEMM unchanged (split-bf16, 3 MFMAs per tile,kstep).
// Epilogue is now sparsity-gated: per (g,ct) the 32-col segment's occupancy
// byte (from k_maskpack) predicates the V/B/mask loads AND the out store.
// ~72.5% of segments are all-zero at 1% mask density -> lines never fetched,
// E_exp never written (k_norm writes those zeros). Segment words for all 16 g
// are prefetched up-front (broadcast u32 loads from the L2-resident 2MB map).
__global__ __launch_bounds__(256, 4) void k_main(const uint4* __restrict__ X1hi,
                                                 const uint4* __restrict__ X1lo,
                                                 const uint4* __restrict__ X2hi,
                                                 const uint4* __restrict__ X2lo,
                                                 const float* __restrict__ V,
                                                 const float* __restrict__ Bm,
                                                 const void* __restrict__ mask,
                                                 const unsigned* __restrict__ flag,
                                                 const uint8_t* __restrict__ segb,
                                                 float* __restrict__ out,
                                                 float* __restrict__ rowsum) {
    int t = threadIdx.x;
    int w = t >> 6, l = t & 63;

    f32x16 acc[4];
#pragma unroll
    for (int ct = 0; ct < 4; ++ct)
#pragma unroll
        for (int e = 0; e < 16; ++e) acc[ct][e] = 0.f;

    const short8* A_hi = (const short8*)X1hi;
    const short8* A_lo = (const short8*)X1lo;
    const short8* B_hi = (const short8*)X2hi;
    const short8* B_lo = (const short8*)X2lo;
    int aT = blockIdx.y * 4 + w;   // row-tile index
    int bT = blockIdx.x * 4;       // first col-tile index

#pragma unroll
    for (int kk = 0; kk < 4; ++kk) {
        short8 ah = A_hi[(aT * 4 + kk) * 64 + l];
        short8 al = A_lo[(aT * 4 + kk) * 64 + l];
#pragma unroll
        for (int ct = 0; ct < 4; ++ct) {
            int bi = ((bT + ct) * 4 + kk) * 64 + l;
            short8 bh = B_hi[bi];
            short8 bl = B_lo[bi];
            acc[ct] = __builtin_amdgcn_mfma_f32_32x32x16_bf16(ah, bl, acc[ct], 0, 0, 0);
            acc[ct] = __builtin_amdgcn_mfma_f32_32x32x16_bf16(al, bh, acc[ct], 0, 0, 0);
            acc[ct] = __builtin_amdgcn_mfma_f32_32x32x16_bf16(ah, bh, acc[ct], 0, 0, 0);
        }
    }

    unsigned fl = *flag;
    int h = l >> 5, c = l & 31;
    int rstrip = blockIdx.y * 128 + w * 32 + h * 4;
    size_t colB = (size_t)blockIdx.x * 128 + c;
    unsigned bx4 = (unsigned)blockIdx.x * 4u;

    // prefetch all 16 segment occupancy words (4 bytes = 4 col-tiles each)
    unsigned segw[16];
#pragma unroll
    for (int g = 0; g < 16; ++g) {
        unsigned row_ = (unsigned)(rstrip + (g & 3) + ((g >> 2) << 3));
        segw[g] = *(const unsigned*)(segb + row_ * 256u + bx4);
    }

    float pv[4], pb[4], pm[4];
    float nv[4], nb[4], nm[4];

#define LOADG(g, av, ab, am)                                                     \
    {                                                                            \
        int row_ = rstrip + ((g) & 3) + (((g) >> 2) << 3);                       \
        size_t base_ = (size_t)row_ * NSQ + colB;                                \
        unsigned sw_ = segw[(g)];                                                \
        _Pragma("unroll")                                                        \
        for (int ct_ = 0; ct_ < 4; ++ct_) {                                      \
            av[ct_] = 0.f; ab[ct_] = 0.f; am[ct_] = 0.f;                         \
            if ((sw_ >> (8 * ct_)) & 0xffu) {                                    \
                av[ct_] = V[base_ + ct_ * 32];                                   \
                ab[ct_] = Bm[base_ + ct_ * 32];                                  \
                if (fl & 2u)                                                     \
                    am[ct_] = (((const float*)mask)[base_ + ct_ * 32] != 0.f) ? 1.f : 0.f; \
                else if (fl & 1u)                                                \
                    am[ct_] = ((const uint8_t*)mask)[base_ + ct_ * 32] ? 1.f : 0.f; \
                else                                                             \
                    am[ct_] = ((const int*)mask)[base_ + ct_ * 32] ? 1.f : 0.f;  \
            }                                                                    \
        }                                                                        \
    }

    LOADG(0, pv, pb, pm);
#pragma unroll
    for (int g = 0; g < 16; ++g) {
        if (g < 15) LOADG(g + 1, nv, nb, nm);
        int row = rstrip + (g & 3) + ((g >> 2) << 3);
        size_t base = (size_t)row * NSQ + colB;
        unsigned sw = segw[g];
        float rsg = 0.f;
#pragma unroll
        for (int ct = 0; ct < 4; ++ct) {
            float e = 0.f;
            if ((sw >> (8 * ct)) & 0xffu) {
                float x  = acc[ct][g] + pb[ct];
                float sg = 1.0f / (1.0f + __expf(-x));
                e = pm[ct] * __expf(pv[ct] * sg);
                out[base + ct * 32] = e;
            }
            rsg += e;
        }
        rsg += __shfl_xor(rsg, 1);
        rsg += __shfl_xor(rsg, 2);
        rsg += __shfl_xor(rsg, 4);
        rsg += __shfl_xor(rsg, 8);
        rsg += __shfl_xor(rsg, 16);
        if (c == 0 && rsg != 0.f) atomicAdd(&rowsum[row], rsg);
#pragma unroll
        for (int ct = 0; ct < 4; ++ct) { pv[ct] = nv[ct]; pb[ct] = nb[ct]; pm[ct] = nm[ct]; }
    }
#undef LOADG
}

// ---------------------------------------------------------------------------
// normalize: A = ee / (rowsum + 1e-6). One row per block. Segment-gated:
// zero segments are stored as zeros WITHOUT reading; active segments (only
// ~27.5% at 1% density, likely L3-resident) are read, scaled, stored.
__global__ __launch_bounds__(256) void k_norm(float* __restrict__ out,
                                              const float* __restrict__ rowsum,
                                              const uint8_t* __restrict__ segb) {
    int row = blockIdx.x;
    int t = threadIdx.x;
    float inv = 1.0f / (rowsum[row] + 1e-6f);
    float4* p = (float4*)out + (size_t)row * 2048;
    const uint8_t* sb = segb + (unsigned)row * 256u;
    uint8_t s[8];
#pragma unroll
    for (int q = 0; q < 8; ++q) s[q] = sb[(t + q * 256) >> 3];
    float4 v[8];
#pragma unroll
    for (int q = 0; q < 8; ++q) {
        v[q] = make_float4(0.f, 0.f, 0.f, 0.f);
        if (s[q]) v[q] = p[t + q * 256];
    }
#pragma unroll
    for (int q = 0; q < 8; ++q) {
        if (s[q]) { v[q].x *= inv; v[q].y *= inv; v[q].z *= inv; v[q].w *= inv; }
        p[t + q * 256] = v[q];
    }
}

// ---------------------------------------------------------------------------
extern "C" void kernel_launch(void* const* d_in, const int* in_sizes, int n_in,
                              void* d_out, int out_size, void* d_ws, size_t ws_size,
                              hipStream_t stream) {
    const float* H    = (const float*)d_in[0];  // [8192,64,64]
    const float* w1   = (const float*)d_in[1];  // [64]
    const float* W2   = (const float*)d_in[2];  // [64,64]
    const float* w3   = (const float*)d_in[3];  // [64]
    const float* V    = (const float*)d_in[4];  // [8192,8192]
    const float* Bm   = (const float*)d_in[5];  // [8192,8192]
    const void*  mask = d_in[6];                // [8192,8192] dtype detected at runtime
    float* out = (float*)d_out;
    float* ws  = (float*)d_ws;

    uint4* X1hi = (uint4*)ws;                   // 65536 uint4 each (1 MB)
    uint4* X1lo = X1hi + 65536;
    uint4* X2hi = X1hi + 131072;
    uint4* X2lo = X1hi + 196608;
    float*    rowsum = ws + WS_RS;
    float*    w2t    = ws + WS_W2T;
    unsigned* flag   = (unsigned*)(ws + WS_FLAG);
    uint8_t*  segb   = (uint8_t*)(ws + WS_SEGB);   // 2 MB occupancy map

    k_init     <<<32,           256, 0, stream>>>(W2, ws);
    k_detect   <<<1024,         256, 0, stream>>>((const uint4*)mask, flag);
    k_prep     <<<2048,         256, 0, stream>>>(H, w1, w3, w2t, X1hi, X1lo, X2hi, X2lo);
    k_maskpack <<<8192,         256, 0, stream>>>(mask, flag, segb);
    k_main     <<<dim3(64, 64), 256, 0, stream>>>(X1hi, X1lo, X2hi, X2lo,
                                                  V, Bm, mask, flag, segb, out, rowsum);
    k_norm     <<<8192,         256, 0, stream>>>(out, rowsum, segb);
}

// Round 2
// 893.727 us; speedup vs baseline: 1.0577x; 1.0577x over previous
//
#include <hip/hip_runtime.h>
#include <stdint.h>

// Problem constants: N_S=8192, N_H=64, C=64
#define NSQ 8192

typedef __attribute__((ext_vector_type(8)))  short short8;   // 8 bf16 (4 VGPRs)
typedef __attribute__((ext_vector_type(16))) float f32x16;   // MFMA 32x32 C/D

// Workspace layout. Packed MFMA fragments first (uint4 units), then floats.
// X1hi/X1lo/X2hi/X2lo: each 65536 uint4 = 1 MB (fragment order, see k_prep).
#define WS_RS   1048576u                  // rowsum [8192] (float offset)
#define WS_W2T  (1048576u + 8192u)        // W2^T [64][64]
#define WS_FLAG (1048576u + 8192u + 4096u)
#define WS_SEGM (1048576u + 8192u + 4096u + 64u)  // bitmap: 8192*256 u32 = 8 MB

// ---------------------------------------------------------------------------
// init: zero rowsum + flag, build W2T (W2T[h*64+i] = W2[i*64+h])
__global__ __launch_bounds__(256) void k_init(const float* __restrict__ W2,
                                              float* __restrict__ ws) {
    int t = threadIdx.x, b = blockIdx.x;
    ws[WS_RS + b * 256 + t] = 0.0f;   // 32 blocks x 256 = 8192
    if (b == 0) {
#pragma unroll
        for (int q = 0; q < 16; ++q) {
            int e = q * 256 + t;
            int i = e >> 6, h = e & 63;
            ws[WS_W2T + h * 64 + i] = W2[i * 64 + h];
        }
        if (t == 0) ((unsigned*)ws)[WS_FLAG] = 0u;
    }
}

// ---------------------------------------------------------------------------
// detect mask dtype from a 4 MB sample.
// f32 mask -> words == 0x3f800000 ; u8 packed -> some word > 1 ; i32 -> {0,1}
__global__ __launch_bounds__(256) void k_detect(const uint4* __restrict__ m,
                                                unsigned* __restrict__ flag) {
    __shared__ unsigned bf;
    int t = threadIdx.x;
    if (t == 0) bf = 0u;
    __syncthreads();
    size_t idx = (size_t)blockIdx.x * 256 + t;
    uint4 v = m[idx];
    unsigned a[4] = {v.x, v.y, v.z, v.w};
    unsigned lf = 0u;
#pragma unroll
    for (int q = 0; q < 4; ++q) {
        if (a[q] == 0x3f800000u) lf |= 2u;
        else if (a[q] > 1u)      lf |= 1u;
    }
    if (lf) atomicOr(&bf, lf);
    __syncthreads();
    if (t == 0 && bf) atomicOr(flag, bf);
}

// ---------------------------------------------------------------------------
// maskpack: build per-segment 32-bit bitmaps. segmask[row*256+seg] bit j =
// (mask[row, seg*32+j] != 0). One block per row, fully coalesced loads,
// words assembled with shfl-OR trees, coalesced u32 writes.
__global__ __launch_bounds__(256) void k_maskpack(const void* __restrict__ mask,
                                                  const unsigned* __restrict__ flag,
                                                  unsigned* __restrict__ segmask) {
    unsigned fl = *flag;
    int row = blockIdx.x;
    int t = threadIdx.x;
    unsigned* sd = segmask + (size_t)row * 256;
    if (fl & 2u) {                       // f32 mask
        const float4* mp = (const float4*)mask + (size_t)row * 2048;
#pragma unroll
        for (int q = 0; q < 8; ++q) {
            float4 v = mp[q * 256 + t];
            unsigned nib = (v.x != 0.f ? 1u : 0u) | (v.y != 0.f ? 2u : 0u) |
                           (v.z != 0.f ? 4u : 0u) | (v.w != 0.f ? 8u : 0u);
            unsigned w = nib << ((t & 7) * 4);
            w |= (unsigned)__shfl_xor((int)w, 1);
            w |= (unsigned)__shfl_xor((int)w, 2);
            w |= (unsigned)__shfl_xor((int)w, 4);
            if ((t & 7) == 0) sd[q * 32 + (t >> 3)] = w;
        }
    } else if (fl & 1u) {                // u8 mask
        const uint4* mp = (const uint4*)mask + (size_t)row * 512;
#pragma unroll
        for (int q = 0; q < 2; ++q) {
            uint4 v = mp[q * 256 + t];
            unsigned a[4] = {v.x, v.y, v.z, v.w};
            unsigned bits = 0u;
#pragma unroll
            for (int k = 0; k < 4; ++k) {
                unsigned u = a[k];
                unsigned nb = ((u & 0xffu) ? 1u : 0u) | ((u & 0xff00u) ? 2u : 0u) |
                              ((u & 0xff0000u) ? 4u : 0u) | ((u & 0xff000000u) ? 8u : 0u);
                bits |= nb << (k * 4);
            }
            unsigned w = bits << ((t & 1) * 16);
            w |= (unsigned)__shfl_xor((int)w, 1);
            if ((t & 1) == 0) sd[q * 128 + (t >> 1)] = w;
        }
    } else {                             // i32 mask
        const uint4* mp = (const uint4*)mask + (size_t)row * 2048;
#pragma unroll
        for (int q = 0; q < 8; ++q) {
            uint4 v = mp[q * 256 + t];
            unsigned nib = (v.x ? 1u : 0u) | (v.y ? 2u : 0u) |
                           (v.z ? 4u : 0u) | (v.w ? 8u : 0u);
            unsigned w = nib << ((t & 7) * 4);
            w |= (unsigned)__shfl_xor((int)w, 1);
            w |= (unsigned)__shfl_xor((int)w, 2);
            w |= (unsigned)__shfl_xor((int)w, 4);
            if ((t & 7) == 0) sd[q * 32 + (t >> 3)] = w;
        }
    }
}

// ---------------------------------------------------------------------------
// round-to-nearest-even fp32 -> bf16 split: x ~= hi + lo
__device__ inline void bf16split(float x, unsigned short& hi, unsigned short& lo) {
    unsigned u = __float_as_uint(x);
    unsigned r = (u + 0x7fffu + ((u >> 16) & 1u)) >> 16;
    hi = (unsigned short)r;
    float res = x - __uint_as_float(r << 16);
    unsigned u2 = __float_as_uint(res);
    unsigned r2 = (u2 + 0x7fffu + ((u2 >> 16) & 1u)) >> 16;
    lo = (unsigned short)r2;
}

// ---------------------------------------------------------------------------
// fused prep: reads H' ONCE (float4), computes
//   Y[s,h]  = sum_c H'[s,c,h]*w1[c]
//   X1[s,i] = sum_h Y[s,h]*W2[i,h]
//   X2[s,c] = sum_h H'[s,c,h]*w3[h]
// then packs X1/X2 rows into split-bf16 MFMA fragment order:
//   chunk (T=s>>5, kk, h, r=s&31) = 8 bf16 of X[s][kk*16+h*8 .. +8]
//   stored at uint4 index (T*4+kk)*64 + h*32 + r
__global__ __launch_bounds__(256) void k_prep(const float* __restrict__ H,
                                              const float* __restrict__ w1,
                                              const float* __restrict__ w3,
                                              const float* __restrict__ w2t,
                                              uint4* __restrict__ X1hi,
                                              uint4* __restrict__ X1lo,
                                              uint4* __restrict__ X2hi,
                                              uint4* __restrict__ X2lo) {
    __shared__ float ylds[4][64];
    __shared__ float x1b[4][64];
    __shared__ float x2b[4][64];
    int t = threadIdx.x;
    int sl = t >> 6, l = t & 63;
    int cq = l >> 4, hq = l & 15;
    size_t s = (size_t)blockIdx.x * 4 + sl;
    const float* hp = H + s * 4096;
    float4 w3q = *(const float4*)(w3 + hq * 4);
    float4 yacc = make_float4(0.f, 0.f, 0.f, 0.f);
    float x2p[16];
#pragma unroll
    for (int cc = 0; cc < 16; ++cc) {
        int c = cq * 16 + cc;
        float4 hv = *(const float4*)(hp + c * 64 + hq * 4);
        float wc = w1[c];
        yacc.x = fmaf(hv.x, wc, yacc.x);
        yacc.y = fmaf(hv.y, wc, yacc.y);
        yacc.z = fmaf(hv.z, wc, yacc.z);
        yacc.w = fmaf(hv.w, wc, yacc.w);
        x2p[cc] = hv.x * w3q.x + hv.y * w3q.y + hv.z * w3q.z + hv.w * w3q.w;
    }
#pragma unroll
    for (int cc = 0; cc < 16; ++cc) {
        float v = x2p[cc];
        v += __shfl_xor(v, 1);
        v += __shfl_xor(v, 2);
        v += __shfl_xor(v, 4);
        v += __shfl_xor(v, 8);
        x2p[cc] = v;
    }
    if (hq == 0) {
#pragma unroll
        for (int cc = 0; cc < 16; ++cc) x2b[sl][cq * 16 + cc] = x2p[cc];
    }
    yacc.x += __shfl_xor(yacc.x, 16); yacc.x += __shfl_xor(yacc.x, 32);
    yacc.y += __shfl_xor(yacc.y, 16); yacc.y += __shfl_xor(yacc.y, 32);
    yacc.z += __shfl_xor(yacc.z, 16); yacc.z += __shfl_xor(yacc.z, 32);
    yacc.w += __shfl_xor(yacc.w, 16); yacc.w += __shfl_xor(yacc.w, 32);
    if (cq == 0) *(float4*)&ylds[sl][hq * 4] = yacc;
    __syncthreads();
    float a1 = 0.f;
#pragma unroll
    for (int h = 0; h < 64; ++h) a1 = fmaf(ylds[sl][h], w2t[h * 64 + l], a1);
    x1b[sl][l] = a1;
    __syncthreads();

    // pack phase: threads 0..63: 4 s-slots x {X1,X2} x 8 k-groups
    if (t < 64) {
        int sl2 = t >> 4;
        int q   = t & 15;
        int mat = q >> 3;       // 0 = X1, 1 = X2
        int kg  = q & 7;        // k-group of 8
        const float* src = mat ? x2b[sl2] : x1b[sl2];
        unsigned short hi8[8], lo8[8];
#pragma unroll
        for (int j = 0; j < 8; ++j) bf16split(src[kg * 8 + j], hi8[j], lo8[j]);
        int sg = blockIdx.x * 4 + sl2;
        int T = sg >> 5, r = sg & 31;
        int kk = kg >> 1, h = kg & 1;
        unsigned ci = (unsigned)((T * 4 + kk) * 64 + h * 32 + r);
        uint4 hv, lv;
        hv.x = (unsigned)hi8[0] | ((unsigned)hi8[1] << 16);
        hv.y = (unsigned)hi8[2] | ((unsigned)hi8[3] << 16);
        hv.z = (unsigned)hi8[4] | ((unsigned)hi8[5] << 16);
        hv.w = (unsigned)hi8[6] | ((unsigned)hi8[7] << 16);
        lv.x = (unsigned)lo8[0] | ((unsigned)lo8[1] << 16);
        lv.y = (unsigned)lo8[2] | ((unsigned)lo8[3] << 16);
        lv.z = (unsigned)lo8[4] | ((unsigned)lo8[5] << 16);
        lv.w = (unsigned)lo8[6] | ((unsigned)lo8[7] << 16);
        if (mat) { X2hi[ci] = hv; X2lo[ci] = lv; }
        else     { X1hi[ci] = hv; X1lo[ci] = lv; }
    }
}

// ---------------------------------------------------------------------------
// main: 128x128 tile per block, 4 independent waves (NO LDS, NO barriers).
// GEMM unchanged (split-bf16, 3 MFMAs per tile,kstep).
// Epilogue: 16-step fully-unrolled software pipeline.
//   - segment bitmap words (uint4/row-tile) prefetched 8 steps ahead (L3-class)
//   - V/B loads (gated on word != 0) prefetched 4 steps ahead (HBM-class)
//   - per-element mask derived from bitmap bits -> NO mask array reads at all
// Static register slots: sm[g&7], pv/pb[(g&3)*4+ct] (full unroll -> no scratch).
__global__ __launch_bounds__(256, 3) void k_main(const uint4* __restrict__ X1hi,
                                                 const uint4* __restrict__ X1lo,
                                                 const uint4* __restrict__ X2hi,
                                                 const uint4* __restrict__ X2lo,
                                                 const float* __restrict__ V,
                                                 const float* __restrict__ Bm,
                                                 const unsigned* __restrict__ segmask,
                                                 float* __restrict__ out,
                                                 float* __restrict__ rowsum) {
    int t = threadIdx.x;
    int w = t >> 6, l = t & 63;

    f32x16 acc[4];
#pragma unroll
    for (int ct = 0; ct < 4; ++ct)
#pragma unroll
        for (int e = 0; e < 16; ++e) acc[ct][e] = 0.f;

    const short8* A_hi = (const short8*)X1hi;
    const short8* A_lo = (const short8*)X1lo;
    const short8* B_hi = (const short8*)X2hi;
    const short8* B_lo = (const short8*)X2lo;
    int aT = blockIdx.y * 4 + w;   // row-tile index
    int bT = blockIdx.x * 4;       // first col-tile index

#pragma unroll
    for (int kk = 0; kk < 4; ++kk) {
        short8 ah = A_hi[(aT * 4 + kk) * 64 + l];
        short8 al = A_lo[(aT * 4 + kk) * 64 + l];
#pragma unroll
        for (int ct = 0; ct < 4; ++ct) {
            int bi = ((bT + ct) * 4 + kk) * 64 + l;
            short8 bh = B_hi[bi];
            short8 bl = B_lo[bi];
            acc[ct] = __builtin_amdgcn_mfma_f32_32x32x16_bf16(ah, bl, acc[ct], 0, 0, 0);
            acc[ct] = __builtin_amdgcn_mfma_f32_32x32x16_bf16(al, bh, acc[ct], 0, 0, 0);
            acc[ct] = __builtin_amdgcn_mfma_f32_32x32x16_bf16(ah, bh, acc[ct], 0, 0, 0);
        }
    }

    int h = l >> 5, c = l & 31;
    int rstrip = blockIdx.y * 128 + w * 32 + h * 4;
    size_t colB = (size_t)blockIdx.x * 128 + c;
    unsigned bx4 = (unsigned)blockIdx.x * 4u;

    uint4 sm[8];          // bitmap words in flight (slot g&7)
    float pv[16], pb[16]; // V/B in flight (slot (g&3)*4+ct)

#define ROWOF(g) (rstrip + ((g) & 3) + (((g) >> 2) << 3))

#define LOADSM(g) sm[(g) & 7] = *(const uint4*)(segmask + (size_t)ROWOF(g) * 256u + bx4);

#define SMW(s_, ct_) ((ct_) == 0 ? (s_).x : (ct_) == 1 ? (s_).y : (ct_) == 2 ? (s_).z : (s_).w)

#define LOADVB(g)                                                                \
    {                                                                            \
        uint4 s_ = sm[(g) & 7];                                                  \
        size_t base_ = (size_t)ROWOF(g) * NSQ + colB;                            \
        _Pragma("unroll")                                                        \
        for (int ct_ = 0; ct_ < 4; ++ct_) {                                      \
            unsigned w_ = SMW(s_, ct_);                                          \
            pv[((g) & 3) * 4 + ct_] = 0.f;                                       \
            pb[((g) & 3) * 4 + ct_] = 0.f;                                       \
            if (w_) {                                                            \
                pv[((g) & 3) * 4 + ct_] = V[base_ + ct_ * 32];                   \
                pb[((g) & 3) * 4 + ct_] = Bm[base_ + ct_ * 32];                  \
            }                                                                    \
        }                                                                        \
    }

    // prologue: 8 bitmap loads, then V/B for first 4 steps
#pragma unroll
    for (int g = 0; g < 8; ++g) { LOADSM(g); }
#pragma unroll
    for (int g = 0; g < 4; ++g) { LOADVB(g); }

#pragma unroll
    for (int g = 0; g < 16; ++g) {
        // ---- compute step g (consumes sm[g&7], pv/pb[(g&3)*4+..]) ----
        int row = ROWOF(g);
        size_t base = (size_t)row * NSQ + colB;
        uint4 s_ = sm[g & 7];
        float rsg = 0.f;
#pragma unroll
        for (int ct = 0; ct < 4; ++ct) {
            unsigned wv = SMW(s_, ct);
            float e = 0.f;
            if (wv) {
                float x  = acc[ct][g] + pb[(g & 3) * 4 + ct];
                float sg = 1.0f / (1.0f + __expf(-x));
                float am = ((wv >> c) & 1u) ? 1.f : 0.f;
                e = am * __expf(pv[(g & 3) * 4 + ct] * sg);
                out[base + ct * 32] = e;
            }
            rsg += e;
        }
        rsg += __shfl_xor(rsg, 1);
        rsg += __shfl_xor(rsg, 2);
        rsg += __shfl_xor(rsg, 4);
        rsg += __shfl_xor(rsg, 8);
        rsg += __shfl_xor(rsg, 16);
        if (c == 0 && rsg != 0.f) atomicAdd(&rowsum[row], rsg);

        // ---- refill pipeline (slots just freed) ----
        if (g + 4 < 16) { LOADVB(g + 4); }
        if (g + 8 < 16) { LOADSM(g + 8); }
    }
#undef LOADVB
#undef SMW
#undef LOADSM
#undef ROWOF
}

// ---------------------------------------------------------------------------
// normalize: A = ee / (rowsum + 1e-6). One row per block. Bitmap-gated:
// zero segments are stored as zeros WITHOUT reading; active segments
// (likely L3-resident from k_main's writes) are read, scaled, stored.
__global__ __launch_bounds__(256) void k_norm(float* __restrict__ out,
                                              const float* __restrict__ rowsum,
                                              const unsigned* __restrict__ segmask) {
    int row = blockIdx.x;
    int t = threadIdx.x;
    float inv = 1.0f / (rowsum[row] + 1e-6f);
    float4* p = (float4*)out + (size_t)row * 2048;
    const unsigned* sd = segmask + (size_t)row * 256;
    unsigned s[8];
#pragma unroll
    for (int q = 0; q < 8; ++q) s[q] = sd[(t + q * 256) >> 3];
    float4 v[8];
#pragma unroll
    for (int q = 0; q < 8; ++q) {
        v[q] = make_float4(0.f, 0.f, 0.f, 0.f);
        if (s[q]) v[q] = p[t + q * 256];
    }
#pragma unroll
    for (int q = 0; q < 8; ++q) {
        if (s[q]) { v[q].x *= inv; v[q].y *= inv; v[q].z *= inv; v[q].w *= inv; }
        p[t + q * 256] = v[q];
    }
}

// ---------------------------------------------------------------------------
extern "C" void kernel_launch(void* const* d_in, const int* in_sizes, int n_in,
                              void* d_out, int out_size, void* d_ws, size_t ws_size,
                              hipStream_t stream) {
    const float* H    = (const float*)d_in[0];  // [8192,64,64]
    const float* w1   = (const float*)d_in[1];  // [64]
    const float* W2   = (const float*)d_in[2];  // [64,64]
    const float* w3   = (const float*)d_in[3];  // [64]
    const float* V    = (const float*)d_in[4];  // [8192,8192]
    const float* Bm   = (const float*)d_in[5];  // [8192,8192]
    const void*  mask = d_in[6];                // [8192,8192] dtype detected at runtime
    float* out = (float*)d_out;
    float* ws  = (float*)d_ws;

    uint4* X1hi = (uint4*)ws;                   // 65536 uint4 each (1 MB)
    uint4* X1lo = X1hi + 65536;
    uint4* X2hi = X1hi + 131072;
    uint4* X2lo = X1hi + 196608;
    float*    rowsum  = ws + WS_RS;
    float*    w2t     = ws + WS_W2T;
    unsigned* flag    = (unsigned*)(ws + WS_FLAG);
    unsigned* segmask = (unsigned*)(ws + WS_SEGM);   // 8 MB bitmap

    k_init     <<<32,           256, 0, stream>>>(W2, ws);
    k_detect   <<<1024,         256, 0, stream>>>((const uint4*)mask, flag);
    k_prep     <<<2048,         256, 0, stream>>>(H, w1, w3, w2t, X1hi, X1lo, X2hi, X2lo);
    k_maskpack <<<8192,         256, 0, stream>>>(mask, flag, segmask);
    k_main     <<<dim3(64, 64), 256, 0, stream>>>(X1hi, X1lo, X2hi, X2lo,
                                                  V, Bm, segmask, out, rowsum);
    k_norm     <<<8192,         256, 0, stream>>>(out, rowsum, segmask);
}

// Round 3
// 875.467 us; speedup vs baseline: 1.0797x; 1.0209x over previous
//
#include <hip/hip_runtime.h>
#include <stdint.h>

// Problem constants: N_S=8192, N_H=64, C=64
#define NSQ 8192

typedef __attribute__((ext_vector_type(8)))  short short8;   // 8 bf16 (4 VGPRs)
typedef __attribute__((ext_vector_type(16))) float f32x16;   // MFMA 32x32 C/D

// Workspace layout. Packed MFMA fragments first (uint4 units), then floats.
// X1hi/X1lo/X2hi/X2lo: each 65536 uint4 = 1 MB (fragment order, see k_prep).
#define WS_W2T  (1048576u + 8192u)        // W2^T [64][64]
#define WS_FLAG (1048576u + 8192u + 4096u)
#define WS_SEGM (1048576u + 8192u + 4096u + 64u)  // bitmap: 8192*256 u32 = 8 MB

// ---------------------------------------------------------------------------
// init: zero flag, build W2T (W2T[h*64+i] = W2[i*64+h]). Single block.
__global__ __launch_bounds__(256) void k_init(const float* __restrict__ W2,
                                              float* __restrict__ ws) {
    int t = threadIdx.x;
#pragma unroll
    for (int q = 0; q < 16; ++q) {
        int e = q * 256 + t;
        int i = e >> 6, h = e & 63;
        ws[WS_W2T + h * 64 + i] = W2[i * 64 + h];
    }
    if (t == 0) ((unsigned*)ws)[WS_FLAG] = 0u;
}

// ---------------------------------------------------------------------------
// detect mask dtype from a 4 MB sample.
// f32 mask -> words == 0x3f800000 ; u8 packed -> some word > 1 ; i32 -> {0,1}
__global__ __launch_bounds__(256) void k_detect(const uint4* __restrict__ m,
                                                unsigned* __restrict__ flag) {
    __shared__ unsigned bf;
    int t = threadIdx.x;
    if (t == 0) bf = 0u;
    __syncthreads();
    size_t idx = (size_t)blockIdx.x * 256 + t;
    uint4 v = m[idx];
    unsigned a[4] = {v.x, v.y, v.z, v.w};
    unsigned lf = 0u;
#pragma unroll
    for (int q = 0; q < 4; ++q) {
        if (a[q] == 0x3f800000u) lf |= 2u;
        else if (a[q] > 1u)      lf |= 1u;
    }
    if (lf) atomicOr(&bf, lf);
    __syncthreads();
    if (t == 0 && bf) atomicOr(flag, bf);
}

// ---------------------------------------------------------------------------
// maskpack: build per-segment 32-bit bitmaps. segmask[row*256+seg] bit j =
// (mask[row, seg*32+j] != 0). One block per row, fully coalesced loads,
// words assembled with shfl-OR trees, coalesced u32 writes.
__global__ __launch_bounds__(256) void k_maskpack(const void* __restrict__ mask,
                                                  const unsigned* __restrict__ flag,
                                                  unsigned* __restrict__ segmask) {
    unsigned fl = *flag;
    int row = blockIdx.x;
    int t = threadIdx.x;
    unsigned* sd = segmask + (size_t)row * 256;
    if (fl & 2u) {                       // f32 mask
        const float4* mp = (const float4*)mask + (size_t)row * 2048;
#pragma unroll
        for (int q = 0; q < 8; ++q) {
            float4 v = mp[q * 256 + t];
            unsigned nib = (v.x != 0.f ? 1u : 0u) | (v.y != 0.f ? 2u : 0u) |
                           (v.z != 0.f ? 4u : 0u) | (v.w != 0.f ? 8u : 0u);
            unsigned w = nib << ((t & 7) * 4);
            w |= (unsigned)__shfl_xor((int)w, 1);
            w |= (unsigned)__shfl_xor((int)w, 2);
            w |= (unsigned)__shfl_xor((int)w, 4);
            if ((t & 7) == 0) sd[q * 32 + (t >> 3)] = w;
        }
    } else if (fl & 1u) {                // u8 mask
        const uint4* mp = (const uint4*)mask + (size_t)row * 512;
#pragma unroll
        for (int q = 0; q < 2; ++q) {
            uint4 v = mp[q * 256 + t];
            unsigned a[4] = {v.x, v.y, v.z, v.w};
            unsigned bits = 0u;
#pragma unroll
            for (int k = 0; k < 4; ++k) {
                unsigned u = a[k];
                unsigned nb = ((u & 0xffu) ? 1u : 0u) | ((u & 0xff00u) ? 2u : 0u) |
                              ((u & 0xff0000u) ? 4u : 0u) | ((u & 0xff000000u) ? 8u : 0u);
                bits |= nb << (k * 4);
            }
            unsigned w = bits << ((t & 1) * 16);
            w |= (unsigned)__shfl_xor((int)w, 1);
            if ((t & 1) == 0) sd[q * 128 + (t >> 1)] = w;
        }
    } else {                             // i32 mask
        const uint4* mp = (const uint4*)mask + (size_t)row * 2048;
#pragma unroll
        for (int q = 0; q < 8; ++q) {
            uint4 v = mp[q * 256 + t];
            unsigned nib = (v.x ? 1u : 0u) | (v.y ? 2u : 0u) |
                           (v.z ? 4u : 0u) | (v.w ? 8u : 0u);
            unsigned w = nib << ((t & 7) * 4);
            w |= (unsigned)__shfl_xor((int)w, 1);
            w |= (unsigned)__shfl_xor((int)w, 2);
            w |= (unsigned)__shfl_xor((int)w, 4);
            if ((t & 7) == 0) sd[q * 32 + (t >> 3)] = w;
        }
    }
}

// ---------------------------------------------------------------------------
// round-to-nearest-even fp32 -> bf16 split: x ~= hi + lo
__device__ inline void bf16split(float x, unsigned short& hi, unsigned short& lo) {
    unsigned u = __float_as_uint(x);
    unsigned r = (u + 0x7fffu + ((u >> 16) & 1u)) >> 16;
    hi = (unsigned short)r;
    float res = x - __uint_as_float(r << 16);
    unsigned u2 = __float_as_uint(res);
    unsigned r2 = (u2 + 0x7fffu + ((u2 >> 16) & 1u)) >> 16;
    lo = (unsigned short)r2;
}

// ---------------------------------------------------------------------------
// fused prep: reads H' ONCE (float4), computes
//   Y[s,h]  = sum_c H'[s,c,h]*w1[c]
//   X1[s,i] = sum_h Y[s,h]*W2[i,h]
//   X2[s,c] = sum_h H'[s,c,h]*w3[h]
// then packs X1/X2 rows into split-bf16 MFMA fragment order:
//   chunk (T=s>>5, kk, h, r=s&31) = 8 bf16 of X[s][kk*16+h*8 .. +8]
//   stored at uint4 index (T*4+kk)*64 + h*32 + r
__global__ __launch_bounds__(256) void k_prep(const float* __restrict__ H,
                                              const float* __restrict__ w1,
                                              const float* __restrict__ w3,
                                              const float* __restrict__ w2t,
                                              uint4* __restrict__ X1hi,
                                              uint4* __restrict__ X1lo,
                                              uint4* __restrict__ X2hi,
                                              uint4* __restrict__ X2lo) {
    __shared__ float ylds[4][64];
    __shared__ float x1b[4][64];
    __shared__ float x2b[4][64];
    int t = threadIdx.x;
    int sl = t >> 6, l = t & 63;
    int cq = l >> 4, hq = l & 15;
    size_t s = (size_t)blockIdx.x * 4 + sl;
    const float* hp = H + s * 4096;
    float4 w3q = *(const float4*)(w3 + hq * 4);
    float4 yacc = make_float4(0.f, 0.f, 0.f, 0.f);
    float x2p[16];
#pragma unroll
    for (int cc = 0; cc < 16; ++cc) {
        int c = cq * 16 + cc;
        float4 hv = *(const float4*)(hp + c * 64 + hq * 4);
        float wc = w1[c];
        yacc.x = fmaf(hv.x, wc, yacc.x);
        yacc.y = fmaf(hv.y, wc, yacc.y);
        yacc.z = fmaf(hv.z, wc, yacc.z);
        yacc.w = fmaf(hv.w, wc, yacc.w);
        x2p[cc] = hv.x * w3q.x + hv.y * w3q.y + hv.z * w3q.z + hv.w * w3q.w;
    }
#pragma unroll
    for (int cc = 0; cc < 16; ++cc) {
        float v = x2p[cc];
        v += __shfl_xor(v, 1);
        v += __shfl_xor(v, 2);
        v += __shfl_xor(v, 4);
        v += __shfl_xor(v, 8);
        x2p[cc] = v;
    }
    if (hq == 0) {
#pragma unroll
        for (int cc = 0; cc < 16; ++cc) x2b[sl][cq * 16 + cc] = x2p[cc];
    }
    yacc.x += __shfl_xor(yacc.x, 16); yacc.x += __shfl_xor(yacc.x, 32);
    yacc.y += __shfl_xor(yacc.y, 16); yacc.y += __shfl_xor(yacc.y, 32);
    yacc.z += __shfl_xor(yacc.z, 16); yacc.z += __shfl_xor(yacc.z, 32);
    yacc.w += __shfl_xor(yacc.w, 16); yacc.w += __shfl_xor(yacc.w, 32);
    if (cq == 0) *(float4*)&ylds[sl][hq * 4] = yacc;
    __syncthreads();
    float a1 = 0.f;
#pragma unroll
    for (int h = 0; h < 64; ++h) a1 = fmaf(ylds[sl][h], w2t[h * 64 + l], a1);
    x1b[sl][l] = a1;
    __syncthreads();

    // pack phase: threads 0..63: 4 s-slots x {X1,X2} x 8 k-groups
    if (t < 64) {
        int sl2 = t >> 4;
        int q   = t & 15;
        int mat = q >> 3;       // 0 = X1, 1 = X2
        int kg  = q & 7;        // k-group of 8
        const float* src = mat ? x2b[sl2] : x1b[sl2];
        unsigned short hi8[8], lo8[8];
#pragma unroll
        for (int j = 0; j < 8; ++j) bf16split(src[kg * 8 + j], hi8[j], lo8[j]);
        int sg = blockIdx.x * 4 + sl2;
        int T = sg >> 5, r = sg & 31;
        int kk = kg >> 1, h = kg & 1;
        unsigned ci = (unsigned)((T * 4 + kk) * 64 + h * 32 + r);
        uint4 hv, lv;
        hv.x = (unsigned)hi8[0] | ((unsigned)hi8[1] << 16);
        hv.y = (unsigned)hi8[2] | ((unsigned)hi8[3] << 16);
        hv.z = (unsigned)hi8[4] | ((unsigned)hi8[5] << 16);
        hv.w = (unsigned)hi8[6] | ((unsigned)hi8[7] << 16);
        lv.x = (unsigned)lo8[0] | ((unsigned)lo8[1] << 16);
        lv.y = (unsigned)lo8[2] | ((unsigned)lo8[3] << 16);
        lv.z = (unsigned)lo8[4] | ((unsigned)lo8[5] << 16);
        lv.w = (unsigned)lo8[6] | ((unsigned)lo8[7] << 16);
        if (mat) { X2hi[ci] = hv; X2lo[ci] = lv; }
        else     { X1hi[ci] = hv; X1lo[ci] = lv; }
    }
}

// ---------------------------------------------------------------------------
// main: 128x128 tile per block, 4 independent waves (NO LDS, NO barriers).
// GEMM unchanged (split-bf16, 3 MFMAs per tile,kstep).
// Epilogue: 16-step fully-unrolled pipeline, NO cross-lane ops (row-sum moved
// to k_norm's block reduce -> no shfl chains, no atomics in the hot loop).
//   - segment bitmap words prefetched 8 steps ahead (L2-class, ring-8)
//   - V/B loads (gated on word != 0) prefetched 6 steps ahead (HBM-class, ring-6)
//   - per-element mask derived from bitmap bits -> NO mask array reads
// Static register slots only (full unroll -> indices constant, no scratch).
__global__ __launch_bounds__(256, 3) void k_main(const uint4* __restrict__ X1hi,
                                                 const uint4* __restrict__ X1lo,
                                                 const uint4* __restrict__ X2hi,
                                                 const uint4* __restrict__ X2lo,
                                                 const float* __restrict__ V,
                                                 const float* __restrict__ Bm,
                                                 const unsigned* __restrict__ segmask,
                                                 float* __restrict__ out) {
    int t = threadIdx.x;
    int w = t >> 6, l = t & 63;

    f32x16 acc[4];
#pragma unroll
    for (int ct = 0; ct < 4; ++ct)
#pragma unroll
        for (int e = 0; e < 16; ++e) acc[ct][e] = 0.f;

    const short8* A_hi = (const short8*)X1hi;
    const short8* A_lo = (const short8*)X1lo;
    const short8* B_hi = (const short8*)X2hi;
    const short8* B_lo = (const short8*)X2lo;
    int aT = blockIdx.y * 4 + w;   // row-tile index
    int bT = blockIdx.x * 4;       // first col-tile index

#pragma unroll
    for (int kk = 0; kk < 4; ++kk) {
        short8 ah = A_hi[(aT * 4 + kk) * 64 + l];
        short8 al = A_lo[(aT * 4 + kk) * 64 + l];
#pragma unroll
        for (int ct = 0; ct < 4; ++ct) {
            int bi = ((bT + ct) * 4 + kk) * 64 + l;
            short8 bh = B_hi[bi];
            short8 bl = B_lo[bi];
            acc[ct] = __builtin_amdgcn_mfma_f32_32x32x16_bf16(ah, bl, acc[ct], 0, 0, 0);
            acc[ct] = __builtin_amdgcn_mfma_f32_32x32x16_bf16(al, bh, acc[ct], 0, 0, 0);
            acc[ct] = __builtin_amdgcn_mfma_f32_32x32x16_bf16(ah, bh, acc[ct], 0, 0, 0);
        }
    }

    int h = l >> 5, c = l & 31;
    int rstrip = blockIdx.y * 128 + w * 32 + h * 4;
    size_t colB = (size_t)blockIdx.x * 128 + c;
    unsigned bx4 = (unsigned)blockIdx.x * 4u;

    uint4 sm[8];          // bitmap words in flight (slot g&7)
    float pv[24], pb[24]; // V/B in flight (slot (g%6)*4+ct)

#define ROWOF(g) (rstrip + ((g) & 3) + (((g) >> 2) << 3))

#define LOADSM(g) sm[(g) & 7] = *(const uint4*)(segmask + (size_t)ROWOF(g) * 256u + bx4);

#define SMW(s_, ct_) ((ct_) == 0 ? (s_).x : (ct_) == 1 ? (s_).y : (ct_) == 2 ? (s_).z : (s_).w)

#define LOADVB(g)                                                                \
    {                                                                            \
        uint4 s_ = sm[(g) & 7];                                                  \
        size_t base_ = (size_t)ROWOF(g) * NSQ + colB;                            \
        _Pragma("unroll")                                                        \
        for (int ct_ = 0; ct_ < 4; ++ct_) {                                      \
            unsigned w_ = SMW(s_, ct_);                                          \
            pv[((g) % 6) * 4 + ct_] = 0.f;                                       \
            pb[((g) % 6) * 4 + ct_] = 0.f;                                       \
            if (w_) {                                                            \
                pv[((g) % 6) * 4 + ct_] = V[base_ + ct_ * 32];                   \
                pb[((g) % 6) * 4 + ct_] = Bm[base_ + ct_ * 32];                  \
            }                                                                    \
        }                                                                        \
    }

    // prologue: 8 bitmap loads, then V/B for first 6 steps
#pragma unroll
    for (int g = 0; g < 8; ++g) { LOADSM(g); }
#pragma unroll
    for (int g = 0; g < 6; ++g) { LOADVB(g); }

#pragma unroll
    for (int g = 0; g < 16; ++g) {
        // ---- compute step g (consumes sm[g&7], pv/pb[(g%6)*4+..]) ----
        int row = ROWOF(g);
        size_t base = (size_t)row * NSQ + colB;
        uint4 s_ = sm[g & 7];
#pragma unroll
        for (int ct = 0; ct < 4; ++ct) {
            unsigned wv = SMW(s_, ct);
            if (wv) {
                float x  = acc[ct][g] + pb[(g % 6) * 4 + ct];
                float sg = 1.0f / (1.0f + __expf(-x));
                float am = ((wv >> c) & 1u) ? 1.f : 0.f;
                float e  = am * __expf(pv[(g % 6) * 4 + ct] * sg);
                out[base + ct * 32] = e;
            }
        }
        // ---- refill pipeline (slots just freed) ----
        if (g + 6 < 16) { LOADVB(g + 6); }
        if (g + 8 < 16) { LOADSM(g + 8); }
    }
#undef LOADVB
#undef SMW
#undef LOADSM
#undef ROWOF
}

// ---------------------------------------------------------------------------
// normalize: A = ee / (rowsum + 1e-6). One row per block. Bitmap-gated reads;
// row-sum computed HERE as a block reduction over the values we read anyway
// (replaces k_main's per-g shfl chains + global atomics). Zero segments are
// written as zeros without reading.
__global__ __launch_bounds__(256) void k_norm(float* __restrict__ out,
                                              const unsigned* __restrict__ segmask) {
    __shared__ float red[4];
    int row = blockIdx.x;
    int t = threadIdx.x;
    float4* p = (float4*)out + (size_t)row * 2048;
    const unsigned* sd = segmask + (size_t)row * 256;
    unsigned s[8];
#pragma unroll
    for (int q = 0; q < 8; ++q) s[q] = sd[(t + q * 256) >> 3];
    float4 v[8];
#pragma unroll
    for (int q = 0; q < 8; ++q) {
        v[q] = make_float4(0.f, 0.f, 0.f, 0.f);
        if (s[q]) v[q] = p[t + q * 256];
    }
    // block row-sum reduce
    float sum = 0.f;
#pragma unroll
    for (int q = 0; q < 8; ++q) sum += (v[q].x + v[q].y) + (v[q].z + v[q].w);
    sum += __shfl_xor(sum, 1);
    sum += __shfl_xor(sum, 2);
    sum += __shfl_xor(sum, 4);
    sum += __shfl_xor(sum, 8);
    sum += __shfl_xor(sum, 16);
    sum += __shfl_xor(sum, 32);
    if ((t & 63) == 0) red[t >> 6] = sum;
    __syncthreads();
    float inv = 1.0f / (((red[0] + red[1]) + (red[2] + red[3])) + 1e-6f);
#pragma unroll
    for (int q = 0; q < 8; ++q) {
        if (s[q]) { v[q].x *= inv; v[q].y *= inv; v[q].z *= inv; v[q].w *= inv; }
        p[t + q * 256] = v[q];
    }
}

// ---------------------------------------------------------------------------
extern "C" void kernel_launch(void* const* d_in, const int* in_sizes, int n_in,
                              void* d_out, int out_size, void* d_ws, size_t ws_size,
                              hipStream_t stream) {
    const float* H    = (const float*)d_in[0];  // [8192,64,64]
    const float* w1   = (const float*)d_in[1];  // [64]
    const float* W2   = (const float*)d_in[2];  // [64,64]
    const float* w3   = (const float*)d_in[3];  // [64]
    const float* V    = (const float*)d_in[4];  // [8192,8192]
    const float* Bm   = (const float*)d_in[5];  // [8192,8192]
    const void*  mask = d_in[6];                // [8192,8192] dtype detected at runtime
    float* out = (float*)d_out;
    float* ws  = (float*)d_ws;

    uint4* X1hi = (uint4*)ws;                   // 65536 uint4 each (1 MB)
    uint4* X1lo = X1hi + 65536;
    uint4* X2hi = X1hi + 131072;
    uint4* X2lo = X1hi + 196608;
    float*    w2t     = ws + WS_W2T;
    unsigned* flag    = (unsigned*)(ws + WS_FLAG);
    unsigned* segmask = (unsigned*)(ws + WS_SEGM);   // 8 MB bitmap

    k_init     <<<1,            256, 0, stream>>>(W2, ws);
    k_detect   <<<1024,         256, 0, stream>>>((const uint4*)mask, flag);
    k_prep     <<<2048,         256, 0, stream>>>(H, w1, w3, w2t, X1hi, X1lo, X2hi, X2lo);
    k_maskpack <<<8192,         256, 0, stream>>>(mask, flag, segmask);
    k_main     <<<dim3(64, 64), 256, 0, stream>>>(X1hi, X1lo, X2hi, X2lo,
                                                  V, Bm, segmask, out);
    k_norm     <<<8192,         256, 0, stream>>>(out, segmask);
}